// Round 10
// baseline (392.513 us; speedup 1.0000x reference)
//
#include <hip/hip_runtime.h>

// ---------------------------------------------------------------------------
// SlotAttention on MI355X (gfx950) — HW kernel-boundary sync ONLY.
// Lessons: r2-5 software grid barriers ~60-70us; r8 in-kernel ACQ_REL tails
// poison L2 while streaming; r9 "fusions" that cut TLP or put serial gathers
// on the chain regress. r10 = r7 (293us, best) + off-chain moves only:
//   K1 prep(1152):  weights->bf16 + slots init (LN moved into kv)
//   K2 kv(272):     LN(inputs) fused into kv GEMM (128-row blocks, 64KB LDS
//                   A-tile) + init q & h_bf (16 blocks)
//   3x K3 attn_gh(560): attn (512 blk, 16 chunks x 64 tok, r7 body) ∥ gh(48)
//      K4 u2b(256):  combine upart -> u_bf (r7 body)
//      K5 gi(4,12):  gi GEMM (r7 gates body, gi half)
//      K6 mlp1f(16,4): GRU (recomputed/strip) + LN_ff + MLP1 (r8 body) -> smid,h1
//      K7 out(16,4): MLP2 partials (r7 body)
//      K8 lnq(16):   reduce + b2 + smid residual + LN + next-q + h_bf
// kv bf16. GEMM LDS XOR-swizzled (slot ^= (row>>1)&3). MFMA layouts m89/m97:
//   A/B: idx = lane&15, k = (lane>>4)*8 + j ; C/D: col = lane&15,
//   row = (lane>>4)*4 + reg
// ---------------------------------------------------------------------------

typedef __attribute__((ext_vector_type(8))) __bf16 bf16x8;
typedef __attribute__((ext_vector_type(4))) float  f32x4;

#define MFMA16(a, b, c) __builtin_amdgcn_mfma_f32_16x16x32_bf16((a), (b), (c), 0, 0, 0)

static __device__ __forceinline__ unsigned short f2bf(float f) {
    unsigned int x = __float_as_uint(f);
    x = (x + 0x7fffu + ((x >> 16) & 1u)) >> 16;   // RN-even
    return (unsigned short)x;
}
static __device__ __forceinline__ float bf2f(unsigned short u) {
    return __uint_as_float((unsigned int)u << 16);
}
static __device__ __forceinline__ float bflo(unsigned int x) {
    return __uint_as_float(x << 16);
}
static __device__ __forceinline__ float bfhi(unsigned int x) {
    return __uint_as_float(x & 0xffff0000u);
}

struct Params {
    const float *inputs, *noise, *mu, *ls;
    const float *Wq, *Wk, *Wv, *wih, *whh, *bih, *bhh, *w1, *b1, *w2, *b2;
    const float *ln_in_g, *ln_in_b, *ln_s_g, *ln_s_b, *ln_ff_g, *ln_ff_b;
    float* out;
    unsigned short *kvW_bf, *Wq_bf, *wih_bf, *whh_bf, *w1_bf, *w2_bf;
    unsigned short *kv_bf, *u_bf, *h_bf, *h1_bf;
    float *slots, *smid, *q, *upart, *rspart, *gi, *gh, *opart;
};

// ---------------- q = ln_s(16 rows in u) @ Wq^T -----------------------------
static __device__ void qgemm(const Params& p, const unsigned short (&u)[16][264], int r0) {
    const int t = threadIdx.x, w = t >> 6, lane = t & 63;
    const int lr = lane & 15, lq = lane >> 4;
    f32x4 acc[4] = {};
    for (int k0 = 0; k0 < 256; k0 += 32) {
        bf16x8 a = *(const bf16x8*)&u[lr][k0 + lq * 8];
        #pragma unroll
        for (int j = 0; j < 4; ++j) {
            bf16x8 bv = *(const bf16x8*)(p.Wq_bf + (size_t)(w * 64 + j * 16 + lr) * 256 + k0 + lq * 8);
            acc[j] = MFMA16(a, bv, acc[j]);
        }
    }
    #pragma unroll
    for (int j = 0; j < 4; ++j)
        #pragma unroll
        for (int r = 0; r < 4; ++r)
            p.q[(size_t)(r0 + lq * 4 + r) * 256 + w * 64 + j * 16 + lr] = acc[j][r];
}

// ============================ K1: prep (weights + slots) ====================
__global__ __launch_bounds__(256) void k_prep(Params p) {
    for (int gid = blockIdx.x * 256 + threadIdx.x; gid < 1179648; gid += 1152 * 256) {
        if      (gid <   65536) p.kvW_bf[gid]          = f2bf(p.Wk[gid]);
        else if (gid <  131072) p.kvW_bf[gid]          = f2bf(p.Wv[gid -   65536]);
        else if (gid <  196608) p.Wq_bf[gid - 131072]  = f2bf(p.Wq[gid -  131072]);
        else if (gid <  393216) p.wih_bf[gid - 196608] = f2bf(p.wih[gid - 196608]);
        else if (gid <  589824) p.whh_bf[gid - 393216] = f2bf(p.whh[gid - 393216]);
        else if (gid <  851968) p.w1_bf[gid - 589824]  = f2bf(p.w1[gid -  589824]);
        else if (gid < 1114112) p.w2_bf[gid - 851968]  = f2bf(p.w2[gid -  851968]);
        else {
            const int i = gid - 1114112;
            const int d = i & 255;
            p.slots[i] = p.mu[d] + expf(p.ls[d]) * p.noise[i];
        }
    }
}

// ============================ K2: LN+kv GEMM + init q/h_bf ==================
// 256 kv blocks: each owns 128 input rows. Phase A: LN (bit-identical wave-
// per-row order as before) -> swizzled bf16 LDS A [128][256]. Phase B: GEMM
// against [Wk;Wv] over 8 n-tiles of 64. Blocks 256..271: init q & h_bf.
union KvSmem {
    struct { unsigned short As[128 * 256]; unsigned short Bs[64 * 32]; } g;  // 68 KB
    unsigned short u[16][264];
};

__global__ __launch_bounds__(256) void k_kv(Params p) {
    __shared__ KvSmem sm;
    const int bid = blockIdx.x, t = threadIdx.x;
    if (bid < 256) {
        const int r0 = bid * 128;
        const int wave = t >> 6, lane = t & 63;
        {   // ---- Phase A: LN rows -> As (swizzled)
            const float g0 = p.ln_in_g[lane * 4 + 0], g1 = p.ln_in_g[lane * 4 + 1];
            const float g2 = p.ln_in_g[lane * 4 + 2], g3 = p.ln_in_g[lane * 4 + 3];
            const float b0 = p.ln_in_b[lane * 4 + 0], b1 = p.ln_in_b[lane * 4 + 1];
            const float b2 = p.ln_in_b[lane * 4 + 2], b3 = p.ln_in_b[lane * 4 + 3];
            const int c = lane * 4;
            const int chunk = c >> 5, sl = (c >> 3) & 3, c7 = c & 7;
            for (int rr = 0; rr < 32; ++rr) {
                const int row = rr * 4 + wave;
                float4 v = *(const float4*)(p.inputs + (size_t)(r0 + row) * 256 + c);
                float s  = v.x + v.y + v.z + v.w;
                float ss = v.x * v.x + v.y * v.y + v.z * v.z + v.w * v.w;
                #pragma unroll
                for (int o = 1; o < 64; o <<= 1) { s += __shfl_xor(s, o); ss += __shfl_xor(ss, o); }
                const float mean = s * (1.f / 256.f);
                const float var  = ss * (1.f / 256.f) - mean * mean;
                const float rstd = rsqrtf(var + 1e-5f);
                ushort4 o4;
                o4.x = f2bf((v.x - mean) * rstd * g0 + b0);
                o4.y = f2bf((v.y - mean) * rstd * g1 + b1);
                o4.z = f2bf((v.z - mean) * rstd * g2 + b2);
                o4.w = f2bf((v.w - mean) * rstd * g3 + b3);
                const int swz = sl ^ ((row >> 1) & 3);
                *(ushort4*)(sm.g.As + row * 256 + chunk * 32 + swz * 8 + c7) = o4;
            }
        }
        __syncthreads();
        // ---- Phase B: GEMM, 8 n-tiles of 64
        const int lr = lane & 15, lq = lane >> 4;
        const int sr = t >> 2, sl2 = t & 3, gk = sl2 * 8;
        const int wsl = (sl2 ^ ((sr >> 1) & 3)) * 8;
        for (int nt = 0; nt < 8; ++nt) {
            const int n0 = nt * 64;
            f32x4 acc[2][4] = {};
            for (int k0 = 0; k0 < 256; k0 += 32) {
                __syncthreads();
                uint4 b0v = *(const uint4*)(p.kvW_bf + (size_t)(n0 + sr) * 256 + k0 + gk);
                *(uint4*)(sm.g.Bs + sr * 32 + wsl) = b0v;
                __syncthreads();
                bf16x8 af[2], bv[4];
                #pragma unroll
                for (int i = 0; i < 2; ++i) {
                    const int ra = wave * 32 + i * 16 + lr;
                    af[i] = *(const bf16x8*)(sm.g.As + ra * 256 + (k0 >> 5) * 32 + ((lq ^ ((ra >> 1) & 3)) * 8));
                }
                #pragma unroll
                for (int j = 0; j < 4; ++j) {
                    const int rb = j * 16 + lr;
                    bv[j] = *(const bf16x8*)(sm.g.Bs + rb * 32 + ((lq ^ ((rb >> 1) & 3)) * 8));
                }
                #pragma unroll
                for (int i = 0; i < 2; ++i)
                    #pragma unroll
                    for (int j = 0; j < 4; ++j)
                        acc[i][j] = MFMA16(af[i], bv[j], acc[i][j]);
            }
            #pragma unroll
            for (int i = 0; i < 2; ++i)
                #pragma unroll
                for (int j = 0; j < 4; ++j) {
                    const int col = n0 + j * 16 + lr;
                    #pragma unroll
                    for (int r = 0; r < 4; ++r) {
                        const int rw = r0 + wave * 32 + i * 16 + lq * 4 + r;
                        p.kv_bf[(size_t)rw * 512 + col] = f2bf(acc[i][j][r]);
                    }
                }
        }
    } else {
        // init: LN(slots) -> q ; h_bf = bf16(slots). blocks 256..271
        const int r0 = (bid - 256) * 16;
        const int row16 = t >> 4, sub = t & 15;
        float vals[16]; float s = 0.f, ss = 0.f;
        #pragma unroll
        for (int k = 0; k < 16; k += 4) {
            float4 v = *(const float4*)(p.slots + (size_t)(r0 + row16) * 256 + sub * 16 + k);
            vals[k] = v.x; vals[k + 1] = v.y; vals[k + 2] = v.z; vals[k + 3] = v.w;
            s += v.x + v.y + v.z + v.w;
            ss += v.x * v.x + v.y * v.y + v.z * v.z + v.w * v.w;
        }
        #pragma unroll
        for (int m = 1; m < 16; m <<= 1) { s += __shfl_xor(s, m); ss += __shfl_xor(ss, m); }
        const float mean = s * (1.f / 256.f);
        const float var  = ss * (1.f / 256.f) - mean * mean;
        const float rstd = rsqrtf(var + 1e-5f);
        #pragma unroll
        for (int k = 0; k < 16; ++k) {
            const int c = sub * 16 + k;
            p.h_bf[(size_t)(r0 + row16) * 256 + c] = f2bf(vals[k]);
            sm.u[row16][c] = f2bf((vals[k] - mean) * rstd * p.ln_s_g[c] + p.ln_s_b[c]);
        }
        __syncthreads();
        qgemm(p, sm.u, r0);
    }
}

// ============================ K3: attn (512, r7 body) ∥ gh GEMM (48) ========
union AtSmem {
    struct { float q[8][260]; float sc[8][68]; } at;             // 10.4 KB
    struct { unsigned short As[64 * 32], Bs[64 * 32]; } g;       // 8 KB
};

__global__ __launch_bounds__(256) void k_attn_gh(Params p) {
    __shared__ AtSmem sm;
    const int bid = blockIdx.x, t = threadIdx.x;
    if (bid < 512) {
        // ---- attention: b = bid>>4, chunk = bid&15 (64 tokens) — r7 body
        const int b = bid >> 4, chunk = bid & 15, j0 = chunk * 64;
        {   // q rows for this batch (8 x 256 f32)
            const int i = t >> 5, c0 = (t & 31) * 8;
            const float* qr = p.q + (size_t)(b * 8 + i) * 256 + c0;
            *(float4*)&sm.at.q[i][c0]     = *(const float4*)(qr);
            *(float4*)&sm.at.q[i][c0 + 4] = *(const float4*)(qr + 4);
        }
        __syncthreads();
        {   // dots for 64 tokens x 8 slots (k in bf16)
            const int i = t & 7, jj = t >> 3;
            const float4* qrow = (const float4*)&sm.at.q[i][0];
            #pragma unroll 1
            for (int g = 0; g < 2; ++g) {
                const int jl = g * 32 + jj;
                const uint4* krow = (const uint4*)(p.kv_bf + ((size_t)b * 1024 + j0 + jl) * 512);
                float a0 = 0, a1 = 0, a2 = 0, a3 = 0;
                #pragma unroll 8
                for (int dd = 0; dd < 32; ++dd) {
                    uint4 kk = krow[dd];
                    float4 q0 = qrow[2 * dd], q1 = qrow[2 * dd + 1];
                    a0 += q0.x * bflo(kk.x); a1 += q0.y * bfhi(kk.x);
                    a2 += q0.z * bflo(kk.y); a3 += q0.w * bfhi(kk.y);
                    a0 += q1.x * bflo(kk.z); a1 += q1.y * bfhi(kk.z);
                    a2 += q1.z * bflo(kk.w); a3 += q1.w * bfhi(kk.w);
                }
                sm.at.sc[i][jl] = (a0 + a1 + a2 + a3) * 0.0625f;   // SCALE
            }
        }
        __syncthreads();
        if (t < 64) {   // softmax over slots per token + EPS
            float v[8], m = -1e30f;
            #pragma unroll
            for (int ii = 0; ii < 8; ++ii) { v[ii] = sm.at.sc[ii][t]; m = fmaxf(m, v[ii]); }
            float s = 0.f;
            #pragma unroll
            for (int ii = 0; ii < 8; ++ii) { v[ii] = __expf(v[ii] - m); s += v[ii]; }
            const float inv = 1.f / s;
            #pragma unroll
            for (int ii = 0; ii < 8; ++ii) sm.at.sc[ii][t] = v[ii] * inv + 1e-8f;
        }
        __syncthreads();
        if (t < 8) {    // per-slot row-sum partial over this 64-token chunk
            float s = 0.f;
            for (int jl = 0; jl < 64; ++jl) s += sm.at.sc[t][jl];
            p.rspart[((size_t)b * 16 + chunk) * 8 + t] = s;
        }
        {   // partial updates: acc[i] += w[i][j] * v[j][d], d = t (v bf16)
            float acc[8] = {};
            const unsigned short* vbase = p.kv_bf + ((size_t)b * 1024 + j0) * 512 + 256 + t;
            #pragma unroll 8
            for (int jl = 0; jl < 64; ++jl) {
                const float vv = bf2f(vbase[(size_t)jl * 512]);
                #pragma unroll
                for (int ii = 0; ii < 8; ++ii) acc[ii] += sm.at.sc[ii][jl] * vv;
            }
            float* up = p.upart + (((size_t)b * 16 + chunk) * 8) * 256 + t;
            #pragma unroll
            for (int ii = 0; ii < 8; ++ii) up[ii * 256] = acc[ii];
        }
    } else {
        // ---- gh GEMM: gh[256,768] = h_bf @ whh^T, 64x64 tiles, 48 blocks
        const int g = bid - 512;
        const int m0 = (g & 3) * 64, n0 = (g >> 2) * 64;
        const int wave = t >> 6, lane = t & 63;
        const int lr = lane & 15, lq = lane >> 4;
        f32x4 acc[4] = {};
        const int sr = t >> 2, sl = t & 3, gk = sl * 8;
        const int wsl = (sl ^ ((sr >> 1) & 3)) * 8;
        for (int k0 = 0; k0 < 256; k0 += 32) {
            __syncthreads();
            uint4 a0 = *(const uint4*)(p.h_bf   + (size_t)(m0 + sr) * 256 + k0 + gk);
            uint4 b0 = *(const uint4*)(p.whh_bf + (size_t)(n0 + sr) * 256 + k0 + gk);
            *(uint4*)(sm.g.As + sr * 32 + wsl) = a0;
            *(uint4*)(sm.g.Bs + sr * 32 + wsl) = b0;
            __syncthreads();
            const int ra = wave * 16 + lr;
            bf16x8 af = *(const bf16x8*)(sm.g.As + ra * 32 + ((lq ^ ((ra >> 1) & 3)) * 8));
            #pragma unroll
            for (int j = 0; j < 4; ++j) {
                const int rb = j * 16 + lr;
                bf16x8 bv = *(const bf16x8*)(sm.g.Bs + rb * 32 + ((lq ^ ((rb >> 1) & 3)) * 8));
                acc[j] = MFMA16(af, bv, acc[j]);
            }
        }
        #pragma unroll
        for (int j = 0; j < 4; ++j) {
            const int col = n0 + j * 16 + lr;
            #pragma unroll
            for (int r = 0; r < 4; ++r)
                p.gh[(size_t)(m0 + wave * 16 + lq * 4 + r) * 768 + col] = acc[j][r];
        }
    }
}

// ============================ K4: combine -> u_bf (r7 body) =================
__global__ __launch_bounds__(256) void k_u2b(Params p) {
    const int row = blockIdx.x, t = threadIdx.x;
    const int b = row >> 3, i = row & 7;
    float acc = 0.f, rs = 0.f;
    #pragma unroll
    for (int c = 0; c < 16; ++c) {
        acc += p.upart[(((size_t)b * 16 + c) * 8 + i) * 256 + t];
        rs  += p.rspart[((size_t)b * 16 + c) * 8 + i];
    }
    p.u_bf[(size_t)row * 256 + t] = f2bf(acc / rs);
}

// ============================ K5: gi GEMM (4,12) ============================
__global__ __launch_bounds__(256) void k_gi(Params p) {
    __shared__ unsigned short As[64 * 32], Bs[64 * 32];
    const int m0 = blockIdx.x * 64, n0 = blockIdx.y * 64;
    const int t = threadIdx.x, wave = t >> 6, lane = t & 63;
    const int lr = lane & 15, lq = lane >> 4;
    f32x4 acc[4] = {};
    const int sr = t >> 2, sl = t & 3, gk = sl * 8;
    const int wsl = (sl ^ ((sr >> 1) & 3)) * 8;
    for (int k0 = 0; k0 < 256; k0 += 32) {
        __syncthreads();
        uint4 a0 = *(const uint4*)(p.u_bf   + (size_t)(m0 + sr) * 256 + k0 + gk);
        uint4 b0 = *(const uint4*)(p.wih_bf + (size_t)(n0 + sr) * 256 + k0 + gk);
        *(uint4*)(As + sr * 32 + wsl) = a0;
        *(uint4*)(Bs + sr * 32 + wsl) = b0;
        __syncthreads();
        const int ra = wave * 16 + lr;
        bf16x8 af = *(const bf16x8*)(As + ra * 32 + ((lq ^ ((ra >> 1) & 3)) * 8));
        #pragma unroll
        for (int j = 0; j < 4; ++j) {
            const int rb = j * 16 + lr;
            bf16x8 bv = *(const bf16x8*)(Bs + rb * 32 + ((lq ^ ((rb >> 1) & 3)) * 8));
            acc[j] = MFMA16(af, bv, acc[j]);
        }
    }
    #pragma unroll
    for (int j = 0; j < 4; ++j) {
        const int col = n0 + j * 16 + lr;
        #pragma unroll
        for (int r = 0; r < 4; ++r)
            p.gi[(size_t)(m0 + wave * 16 + lq * 4 + r) * 768 + col] = acc[j][r];
    }
}

// ============================ K6: GRU + LN_ff + MLP1 (r8 body) ==============
// grid (16, 4): m-strip 16 rows x n-chunk 256 of 1024. GRU recomputed per
// strip; by==0 writes slots_mid -> smid (slots itself stays slots_prev).
__global__ __launch_bounds__(256) void k_mlp1f(Params p) {
    __shared__ unsigned short ff[16][264];
    const int t = threadIdx.x;
    const int r0 = blockIdx.x * 16, nb = blockIdx.y * 256;
    const int row16 = t >> 4, sub = t & 15;
    const int grow = r0 + row16;
    const float* gir = p.gi + (size_t)grow * 768;
    const float* ghr = p.gh + (size_t)grow * 768;
    float vals[16]; float s_ = 0.f, ss = 0.f;
    #pragma unroll
    for (int k = 0; k < 16; ++k) {
        const int c = sub * 16 + k;
        const float ir  = gir[c]       + p.bih[c];
        const float iz  = gir[256 + c] + p.bih[256 + c];
        const float in_ = gir[512 + c] + p.bih[512 + c];
        const float hr  = ghr[c]       + p.bhh[c];
        const float hz  = ghr[256 + c] + p.bhh[256 + c];
        const float hn  = ghr[512 + c] + p.bhh[512 + c];
        const float r = 1.f / (1.f + __expf(-(ir + hr)));
        const float z = 1.f / (1.f + __expf(-(iz + hz)));
        const float n = tanhf(in_ + r * hn);
        const float h = p.slots[(size_t)grow * 256 + c];
        const float s = (1.f - z) * n + z * h;
        if (blockIdx.y == 0) p.smid[(size_t)grow * 256 + c] = s;
        vals[k] = s; s_ += s; ss += s * s;
    }
    #pragma unroll
    for (int m = 1; m < 16; m <<= 1) { s_ += __shfl_xor(s_, m); ss += __shfl_xor(ss, m); }
    const float mean = s_ * (1.f / 256.f);
    const float var  = ss * (1.f / 256.f) - mean * mean;
    const float rstd = rsqrtf(var + 1e-5f);
    #pragma unroll
    for (int k = 0; k < 16; ++k) {
        const int c = sub * 16 + k;
        ff[row16][c] = f2bf((vals[k] - mean) * rstd * p.ln_ff_g[c] + p.ln_ff_b[c]);
    }
    __syncthreads();
    const int w = t >> 6, lane = t & 63, lr = lane & 15, lq = lane >> 4;
    f32x4 acc[4] = {};
    for (int k0 = 0; k0 < 256; k0 += 32) {
        bf16x8 a = *(const bf16x8*)&ff[lr][k0 + lq * 8];
        #pragma unroll
        for (int j = 0; j < 4; ++j) {
            bf16x8 bv = *(const bf16x8*)(p.w1_bf + (size_t)(nb + w * 64 + j * 16 + lr) * 256 + k0 + lq * 8);
            acc[j] = MFMA16(a, bv, acc[j]);
        }
    }
    #pragma unroll
    for (int j = 0; j < 4; ++j) {
        const int col = nb + w * 64 + j * 16 + lr;
        const float bb = p.b1[col];
        #pragma unroll
        for (int r = 0; r < 4; ++r)
            p.h1_bf[(size_t)(r0 + lq * 4 + r) * 1024 + col] = f2bf(fmaxf(acc[j][r] + bb, 0.f));
    }
}

// ============================ K7: MLP2 partials (r7 body) ===================
__global__ __launch_bounds__(256) void k_out(Params p) {
    __shared__ unsigned short a_s[16][264];
    const int t = threadIdx.x;
    const int r0 = blockIdx.x * 16, kb = blockIdx.y * 256;
    const int row16 = t >> 4, sub = t & 15;
    {
        const unsigned short* src = p.h1_bf + (size_t)(r0 + row16) * 1024 + kb + sub * 16;
        *(uint4*)&a_s[row16][sub * 16]     = *(const uint4*)(src);
        *(uint4*)&a_s[row16][sub * 16 + 8] = *(const uint4*)(src + 8);
    }
    __syncthreads();
    const int w = t >> 6, lane = t & 63;
    const int lr = lane & 15, lq = lane >> 4;
    f32x4 acc[4] = {};
    for (int k0 = 0; k0 < 256; k0 += 32) {
        bf16x8 a = *(const bf16x8*)&a_s[lr][k0 + lq * 8];
        #pragma unroll
        for (int j = 0; j < 4; ++j) {
            bf16x8 bv = *(const bf16x8*)(p.w2_bf + (size_t)(w * 64 + j * 16 + lr) * 1024 + kb + k0 + lq * 8);
            acc[j] = MFMA16(a, bv, acc[j]);
        }
    }
    #pragma unroll
    for (int j = 0; j < 4; ++j)
        #pragma unroll
        for (int r = 0; r < 4; ++r)
            p.opart[((size_t)blockIdx.y * 256 + r0 + lq * 4 + r) * 256 + w * 64 + j * 16 + lr] = acc[j][r];
}

// ============================ K8: reduce + residual + LN + q ================
template<int LAST>
__global__ __launch_bounds__(256) void k_lnq(Params p) {
    __shared__ unsigned short u[16][264];
    const int t = threadIdx.x;
    const int r0 = blockIdx.x * 16;
    const int row16 = t >> 4, sub = t & 15;
    float vals[16]; float s_ = 0.f, ss = 0.f;
    #pragma unroll
    for (int k = 0; k < 16; ++k) {
        const int c = sub * 16 + k;
        const size_t ridx = (size_t)(r0 + row16) * 256 + c;
        float v = p.opart[(size_t)(r0 + row16) * 256 + c]
                + p.opart[((size_t)256 + r0 + row16) * 256 + c]
                + p.opart[((size_t)512 + r0 + row16) * 256 + c]
                + p.opart[((size_t)768 + r0 + row16) * 256 + c]
                + p.b2[c] + p.smid[ridx];
        if (LAST) { p.out[ridx] = v; }
        else {
            p.slots[ridx] = v;
            p.h_bf[ridx]  = f2bf(v);
        }
        vals[k] = v; s_ += v; ss += v * v;
    }
    if (LAST) return;
    #pragma unroll
    for (int m = 1; m < 16; m <<= 1) { s_ += __shfl_xor(s_, m); ss += __shfl_xor(ss, m); }
    const float mean = s_ * (1.f / 256.f);
    const float var  = ss * (1.f / 256.f) - mean * mean;
    const float rstd = rsqrtf(var + 1e-5f);
    #pragma unroll
    for (int k = 0; k < 16; ++k) {
        const int c = sub * 16 + k;
        u[row16][c] = f2bf((vals[k] - mean) * rstd * p.ln_s_g[c] + p.ln_s_b[c]);
    }
    __syncthreads();
    qgemm(p, u, r0);
}

// ---------------------------------------------------------------------------
extern "C" void kernel_launch(void* const* d_in, const int* in_sizes, int n_in,
                              void* d_out, int out_size, void* d_ws, size_t ws_size,
                              hipStream_t stream)
{
    (void)in_sizes; (void)n_in; (void)out_size; (void)ws_size;

    Params prm;
    prm.inputs  = (const float*)d_in[0];
    prm.noise   = (const float*)d_in[1];
    prm.mu      = (const float*)d_in[2];
    prm.ls      = (const float*)d_in[3];
    prm.Wq      = (const float*)d_in[4];
    prm.Wk      = (const float*)d_in[5];
    prm.Wv      = (const float*)d_in[6];
    prm.wih     = (const float*)d_in[7];
    prm.whh     = (const float*)d_in[8];
    prm.bih     = (const float*)d_in[9];
    prm.bhh     = (const float*)d_in[10];
    prm.w1      = (const float*)d_in[11];
    prm.b1      = (const float*)d_in[12];
    prm.w2      = (const float*)d_in[13];
    prm.b2      = (const float*)d_in[14];
    prm.ln_in_g = (const float*)d_in[15];
    prm.ln_in_b = (const float*)d_in[16];
    prm.ln_s_g  = (const float*)d_in[17];
    prm.ln_s_b  = (const float*)d_in[18];
    prm.ln_ff_g = (const float*)d_in[19];
    prm.ln_ff_b = (const float*)d_in[20];
    prm.out     = (float*)d_out;

    char* ptr = (char*)d_ws;
    auto alloc = [&](size_t bytes) -> char* {
        char* r = ptr; ptr += (bytes + 255) & ~(size_t)255; return r;
    };
    prm.kv_bf  = (unsigned short*)alloc((size_t)32768 * 512 * 2);
    prm.kvW_bf = (unsigned short*)alloc(512 * 256 * 2);
    prm.Wq_bf  = (unsigned short*)alloc(256 * 256 * 2);
    prm.wih_bf = (unsigned short*)alloc(768 * 256 * 2);
    prm.whh_bf = (unsigned short*)alloc(768 * 256 * 2);
    prm.w1_bf  = (unsigned short*)alloc(1024 * 256 * 2);
    prm.w2_bf  = (unsigned short*)alloc(256 * 1024 * 2);
    prm.slots  = (float*)         alloc(256 * 256 * 4);
    prm.smid   = (float*)         alloc(256 * 256 * 4);
    prm.q      = (float*)         alloc(256 * 256 * 4);
    prm.upart  = (float*)         alloc((size_t)32 * 16 * 8 * 256 * 4);
    prm.rspart = (float*)         alloc(32 * 16 * 8 * 4);
    prm.u_bf   = (unsigned short*)alloc(256 * 256 * 2);
    prm.h_bf   = (unsigned short*)alloc(256 * 256 * 2);
    prm.gi     = (float*)         alloc(256 * 768 * 4);
    prm.gh     = (float*)         alloc(256 * 768 * 4);
    prm.h1_bf  = (unsigned short*)alloc(256 * 1024 * 2);
    prm.opart  = (float*)         alloc((size_t)4 * 256 * 256 * 4);

    k_prep<<<1152, 256, 0, stream>>>(prm);
    k_kv  <<<272, 256, 0, stream>>>(prm);
    for (int it = 0; it < 3; ++it) {
        k_attn_gh<<<560, 256, 0, stream>>>(prm);
        k_u2b    <<<256, 256, 0, stream>>>(prm);
        k_gi     <<<dim3(4, 12), 256, 0, stream>>>(prm);
        k_mlp1f  <<<dim3(16, 4), 256, 0, stream>>>(prm);
        k_out    <<<dim3(16, 4), 256, 0, stream>>>(prm);
        if (it < 2) k_lnq<0><<<16, 256, 0, stream>>>(prm);
        else        k_lnq<1><<<16, 256, 0, stream>>>(prm);
    }
}

// Round 11
// 296.206 us; speedup vs baseline: 1.3251x; 1.3251x over previous
//
#include <hip/hip_runtime.h>

// ---------------------------------------------------------------------------
// SlotAttention on MI355X (gfx950) — HW kernel-boundary sync ONLY.
// Lessons: r2-5 software grid barriers ~60-70us; r8 in-kernel ACQ_REL tails
// poison L2; r9/r10 bundled rewrites regress (serial combine, LN-fused kv at
// 2 blk/CU). r11 = r7 (293us, best) + ONE off-chain move, verbatim pieces:
//   K1 prep(4608): weights->bf16 + slots init + LN(inputs)->bf16   (r7 body)
//   K2 kv(1040):   kv_bf GEMM + init q & h_bf                      (r7 body)
//   3x K3 attn_gh(560): attn (512 blk, r7 body) ∥ gh GEMM (48 blk, r7 gates
//                       body) — gh rides the attn launch, off-chain
//      K4 u2b(256):  combine upart -> u_bf                         (r7 body)
//      K5 gi(4,12):  gi GEMM                                       (r10 body)
//      K6 gruln(256): GRU elementwise + LN_ff                      (r7 body)
//      K7 mlp1(4,16): MLP1 relu -> bf16                            (r7 body)
//      K8 out(16,4):  MLP2 partials                                (r7 body)
//      K9 lnq(16):    reduce + residual + LN + next-q + h_bf       (r7 body)
// kv bf16. GEMM LDS XOR-swizzled (slot ^= (row>>1)&3). MFMA layouts m89/m97:
//   A/B: idx = lane&15, k = (lane>>4)*8 + j ; C/D: col = lane&15,
//   row = (lane>>4)*4 + reg
// ---------------------------------------------------------------------------

typedef __attribute__((ext_vector_type(8))) __bf16 bf16x8;
typedef __attribute__((ext_vector_type(4))) float  f32x4;

#define MFMA16(a, b, c) __builtin_amdgcn_mfma_f32_16x16x32_bf16((a), (b), (c), 0, 0, 0)

static __device__ __forceinline__ unsigned short f2bf(float f) {
    unsigned int x = __float_as_uint(f);
    x = (x + 0x7fffu + ((x >> 16) & 1u)) >> 16;   // RN-even
    return (unsigned short)x;
}
static __device__ __forceinline__ float bf2f(unsigned short u) {
    return __uint_as_float((unsigned int)u << 16);
}
static __device__ __forceinline__ float bflo(unsigned int x) {
    return __uint_as_float(x << 16);
}
static __device__ __forceinline__ float bfhi(unsigned int x) {
    return __uint_as_float(x & 0xffff0000u);
}

struct Params {
    const float *inputs, *noise, *mu, *ls;
    const float *Wq, *Wk, *Wv, *wih, *whh, *bih, *bhh, *w1, *b1, *w2, *b2;
    const float *ln_in_g, *ln_in_b, *ln_s_g, *ln_s_b, *ln_ff_g, *ln_ff_b;
    float* out;
    unsigned short *x_bf, *kvW_bf, *Wq_bf, *wih_bf, *whh_bf, *w1_bf, *w2_bf;
    unsigned short *kv_bf, *u_bf, *h_bf, *ff_bf, *h1_bf;
    float *slots, *q, *upart, *rspart, *gi, *gh, *opart;
};

// ---------------- q = ln_s(16 rows in u) @ Wq^T -----------------------------
static __device__ void qgemm(const Params& p, const unsigned short (&u)[16][264], int r0) {
    const int t = threadIdx.x, w = t >> 6, lane = t & 63;
    const int lr = lane & 15, lq = lane >> 4;
    f32x4 acc[4] = {};
    for (int k0 = 0; k0 < 256; k0 += 32) {
        bf16x8 a = *(const bf16x8*)&u[lr][k0 + lq * 8];
        #pragma unroll
        for (int j = 0; j < 4; ++j) {
            bf16x8 bv = *(const bf16x8*)(p.Wq_bf + (size_t)(w * 64 + j * 16 + lr) * 256 + k0 + lq * 8);
            acc[j] = MFMA16(a, bv, acc[j]);
        }
    }
    #pragma unroll
    for (int j = 0; j < 4; ++j)
        #pragma unroll
        for (int r = 0; r < 4; ++r)
            p.q[(size_t)(r0 + lq * 4 + r) * 256 + w * 64 + j * 16 + lr] = acc[j][r];
}

// ============================ K1: prep + LN(inputs) =========================
__global__ __launch_bounds__(256) void k_prep(Params p) {
    const int bid = blockIdx.x, t = threadIdx.x;
    for (int gid = bid * 256 + t; gid < 1179648; gid += 4608 * 256) {
        if      (gid <   65536) p.kvW_bf[gid]          = f2bf(p.Wk[gid]);
        else if (gid <  131072) p.kvW_bf[gid]          = f2bf(p.Wv[gid -   65536]);
        else if (gid <  196608) p.Wq_bf[gid - 131072]  = f2bf(p.Wq[gid -  131072]);
        else if (gid <  393216) p.wih_bf[gid - 196608] = f2bf(p.wih[gid - 196608]);
        else if (gid <  589824) p.whh_bf[gid - 393216] = f2bf(p.whh[gid - 393216]);
        else if (gid <  851968) p.w1_bf[gid - 589824]  = f2bf(p.w1[gid -  589824]);
        else if (gid < 1114112) p.w2_bf[gid - 851968]  = f2bf(p.w2[gid -  851968]);
        else {
            const int i = gid - 1114112;
            const int d = i & 255;
            p.slots[i] = p.mu[d] + expf(p.ls[d]) * p.noise[i];
        }
    }
    const int wid  = (bid * 256 + t) >> 6;
    const int lane = t & 63;
    const float g0 = p.ln_in_g[lane * 4 + 0], g1 = p.ln_in_g[lane * 4 + 1];
    const float g2 = p.ln_in_g[lane * 4 + 2], g3 = p.ln_in_g[lane * 4 + 3];
    const float b0 = p.ln_in_b[lane * 4 + 0], b1 = p.ln_in_b[lane * 4 + 1];
    const float b2 = p.ln_in_b[lane * 4 + 2], b3 = p.ln_in_b[lane * 4 + 3];
    #pragma unroll 2
    for (int row = wid; row < 32768; row += 18432) {
        float4 v = *(const float4*)(p.inputs + (size_t)row * 256 + lane * 4);
        float s  = v.x + v.y + v.z + v.w;
        float ss = v.x * v.x + v.y * v.y + v.z * v.z + v.w * v.w;
        #pragma unroll
        for (int o = 1; o < 64; o <<= 1) { s += __shfl_xor(s, o); ss += __shfl_xor(ss, o); }
        float mean = s * (1.f / 256.f);
        float var  = ss * (1.f / 256.f) - mean * mean;
        float rstd = rsqrtf(var + 1e-5f);
        ushort4 o4;
        o4.x = f2bf((v.x - mean) * rstd * g0 + b0);
        o4.y = f2bf((v.y - mean) * rstd * g1 + b1);
        o4.z = f2bf((v.z - mean) * rstd * g2 + b2);
        o4.w = f2bf((v.w - mean) * rstd * g3 + b3);
        *(ushort4*)(p.x_bf + (size_t)row * 256 + lane * 4) = o4;
    }
}

// ============================ K2: kv GEMM + init q/h_bf =====================
union KvSmem {
    struct { unsigned short As[128 * 32], Bs[128 * 32]; } g;   // 16 KB
    unsigned short u[16][264];                                  // 8.25 KB
};

__global__ __launch_bounds__(256) void k_kv(Params p) {
    __shared__ KvSmem sm;
    const int bid = blockIdx.x, t = threadIdx.x;
    if (bid < 1024) {
        const int m0 = (bid >> 2) * 128, n0 = (bid & 3) * 128;
        const int wave = t >> 6, lane = t & 63;
        const int qr = (wave >> 1) * 64, qc = (wave & 1) * 64;
        const int lr = lane & 15, lq = lane >> 4;
        f32x4 acc[4][4] = {};
        const int sr = t >> 2, sl = t & 3, gk = sl * 8;
        const int wsl0 = (sl ^ ((sr >> 1) & 3)) * 8;
        const int wsl1 = (sl ^ (((sr + 64) >> 1) & 3)) * 8;
        for (int k0 = 0; k0 < 256; k0 += 32) {
            __syncthreads();
            uint4 a0 = *(const uint4*)(p.x_bf   + (size_t)(m0 + sr)      * 256 + k0 + gk);
            uint4 a1 = *(const uint4*)(p.x_bf   + (size_t)(m0 + sr + 64) * 256 + k0 + gk);
            uint4 b0 = *(const uint4*)(p.kvW_bf + (size_t)(n0 + sr)      * 256 + k0 + gk);
            uint4 b1 = *(const uint4*)(p.kvW_bf + (size_t)(n0 + sr + 64) * 256 + k0 + gk);
            *(uint4*)(sm.g.As + sr * 32 + wsl0) = a0;
            *(uint4*)(sm.g.As + (sr + 64) * 32 + wsl1) = a1;
            *(uint4*)(sm.g.Bs + sr * 32 + wsl0) = b0;
            *(uint4*)(sm.g.Bs + (sr + 64) * 32 + wsl1) = b1;
            __syncthreads();
            bf16x8 af[4], bv[4];
            #pragma unroll
            for (int i = 0; i < 4; i++) {
                const int ra = qr + i * 16 + lr;
                af[i] = *(const bf16x8*)(sm.g.As + ra * 32 + ((lq ^ ((ra >> 1) & 3)) * 8));
            }
            #pragma unroll
            for (int i = 0; i < 4; i++) {
                const int rb = qc + i * 16 + lr;
                bv[i] = *(const bf16x8*)(sm.g.Bs + rb * 32 + ((lq ^ ((rb >> 1) & 3)) * 8));
            }
            #pragma unroll
            for (int i = 0; i < 4; i++)
                #pragma unroll
                for (int j = 0; j < 4; j++)
                    acc[i][j] = MFMA16(af[i], bv[j], acc[i][j]);
        }
        #pragma unroll
        for (int i = 0; i < 4; i++)
            #pragma unroll
            for (int j = 0; j < 4; j++) {
                const int col = n0 + qc + j * 16 + lr;
                #pragma unroll
                for (int r = 0; r < 4; r++) {
                    const int rw = m0 + qr + i * 16 + lq * 4 + r;
                    p.kv_bf[(size_t)rw * 512 + col] = f2bf(acc[i][j][r]);
                }
            }
    } else {
        // init: LN(slots) -> q ; h_bf = bf16(slots). blocks 1024..1039
        const int r0 = (bid - 1024) * 16;
        const int row16 = t >> 4, sub = t & 15;
        float vals[16]; float s = 0.f, ss = 0.f;
        #pragma unroll
        for (int k = 0; k < 16; k += 4) {
            float4 v = *(const float4*)(p.slots + (size_t)(r0 + row16) * 256 + sub * 16 + k);
            vals[k] = v.x; vals[k + 1] = v.y; vals[k + 2] = v.z; vals[k + 3] = v.w;
            s += v.x + v.y + v.z + v.w;
            ss += v.x * v.x + v.y * v.y + v.z * v.z + v.w * v.w;
        }
        #pragma unroll
        for (int m = 1; m < 16; m <<= 1) { s += __shfl_xor(s, m); ss += __shfl_xor(ss, m); }
        const float mean = s * (1.f / 256.f);
        const float var  = ss * (1.f / 256.f) - mean * mean;
        const float rstd = rsqrtf(var + 1e-5f);
        #pragma unroll
        for (int k = 0; k < 16; ++k) {
            const int c = sub * 16 + k;
            p.h_bf[(size_t)(r0 + row16) * 256 + c] = f2bf(vals[k]);
            sm.u[row16][c] = f2bf((vals[k] - mean) * rstd * p.ln_s_g[c] + p.ln_s_b[c]);
        }
        __syncthreads();
        qgemm(p, sm.u, r0);
    }
}

// ============================ K3: attn (512, r7 body) ∥ gh GEMM (48) ========
union AtSmem {
    struct { float q[8][260]; float sc[8][68]; } at;             // 10.4 KB
    struct { unsigned short As[64 * 32], Bs[64 * 32]; } g;       // 8 KB
};

__global__ __launch_bounds__(256) void k_attn_gh(Params p) {
    __shared__ AtSmem sm;
    const int bid = blockIdx.x, t = threadIdx.x;
    if (bid < 512) {
        // ---- attention: b = bid>>4, chunk = bid&15 (64 tokens) — r7 body
        const int b = bid >> 4, chunk = bid & 15, j0 = chunk * 64;
        {   // q rows for this batch (8 x 256 f32)
            const int i = t >> 5, c0 = (t & 31) * 8;
            const float* qr = p.q + (size_t)(b * 8 + i) * 256 + c0;
            *(float4*)&sm.at.q[i][c0]     = *(const float4*)(qr);
            *(float4*)&sm.at.q[i][c0 + 4] = *(const float4*)(qr + 4);
        }
        __syncthreads();
        {   // dots for 64 tokens x 8 slots (k in bf16)
            const int i = t & 7, jj = t >> 3;
            const float4* qrow = (const float4*)&sm.at.q[i][0];
            #pragma unroll 1
            for (int g = 0; g < 2; ++g) {
                const int jl = g * 32 + jj;
                const uint4* krow = (const uint4*)(p.kv_bf + ((size_t)b * 1024 + j0 + jl) * 512);
                float a0 = 0, a1 = 0, a2 = 0, a3 = 0;
                #pragma unroll 8
                for (int dd = 0; dd < 32; ++dd) {
                    uint4 kk = krow[dd];
                    float4 q0 = qrow[2 * dd], q1 = qrow[2 * dd + 1];
                    a0 += q0.x * bflo(kk.x); a1 += q0.y * bfhi(kk.x);
                    a2 += q0.z * bflo(kk.y); a3 += q0.w * bfhi(kk.y);
                    a0 += q1.x * bflo(kk.z); a1 += q1.y * bfhi(kk.z);
                    a2 += q1.z * bflo(kk.w); a3 += q1.w * bfhi(kk.w);
                }
                sm.at.sc[i][jl] = (a0 + a1 + a2 + a3) * 0.0625f;   // SCALE
            }
        }
        __syncthreads();
        if (t < 64) {   // softmax over slots per token + EPS
            float v[8], m = -1e30f;
            #pragma unroll
            for (int ii = 0; ii < 8; ++ii) { v[ii] = sm.at.sc[ii][t]; m = fmaxf(m, v[ii]); }
            float s = 0.f;
            #pragma unroll
            for (int ii = 0; ii < 8; ++ii) { v[ii] = __expf(v[ii] - m); s += v[ii]; }
            const float inv = 1.f / s;
            #pragma unroll
            for (int ii = 0; ii < 8; ++ii) sm.at.sc[ii][t] = v[ii] * inv + 1e-8f;
        }
        __syncthreads();
        if (t < 8) {    // per-slot row-sum partial over this 64-token chunk
            float s = 0.f;
            for (int jl = 0; jl < 64; ++jl) s += sm.at.sc[t][jl];
            p.rspart[((size_t)b * 16 + chunk) * 8 + t] = s;
        }
        {   // partial updates: acc[i] += w[i][j] * v[j][d], d = t (v bf16)
            float acc[8] = {};
            const unsigned short* vbase = p.kv_bf + ((size_t)b * 1024 + j0) * 512 + 256 + t;
            #pragma unroll 8
            for (int jl = 0; jl < 64; ++jl) {
                const float vv = bf2f(vbase[(size_t)jl * 512]);
                #pragma unroll
                for (int ii = 0; ii < 8; ++ii) acc[ii] += sm.at.sc[ii][jl] * vv;
            }
            float* up = p.upart + (((size_t)b * 16 + chunk) * 8) * 256 + t;
            #pragma unroll
            for (int ii = 0; ii < 8; ++ii) up[ii * 256] = acc[ii];
        }
    } else {
        // ---- gh GEMM: gh[256,768] = h_bf @ whh^T, 64x64 tiles, 48 blocks
        const int g = bid - 512;
        const int m0 = (g & 3) * 64, n0 = (g >> 2) * 64;
        const int wave = t >> 6, lane = t & 63;
        const int lr = lane & 15, lq = lane >> 4;
        f32x4 acc[4] = {};
        const int sr = t >> 2, sl = t & 3, gk = sl * 8;
        const int wsl = (sl ^ ((sr >> 1) & 3)) * 8;
        for (int k0 = 0; k0 < 256; k0 += 32) {
            __syncthreads();
            uint4 a0 = *(const uint4*)(p.h_bf   + (size_t)(m0 + sr) * 256 + k0 + gk);
            uint4 b0 = *(const uint4*)(p.whh_bf + (size_t)(n0 + sr) * 256 + k0 + gk);
            *(uint4*)(sm.g.As + sr * 32 + wsl) = a0;
            *(uint4*)(sm.g.Bs + sr * 32 + wsl) = b0;
            __syncthreads();
            const int ra = wave * 16 + lr;
            bf16x8 af = *(const bf16x8*)(sm.g.As + ra * 32 + ((lq ^ ((ra >> 1) & 3)) * 8));
            #pragma unroll
            for (int j = 0; j < 4; ++j) {
                const int rb = j * 16 + lr;
                bf16x8 bv = *(const bf16x8*)(sm.g.Bs + rb * 32 + ((lq ^ ((rb >> 1) & 3)) * 8));
                acc[j] = MFMA16(af, bv, acc[j]);
            }
        }
        #pragma unroll
        for (int j = 0; j < 4; ++j) {
            const int col = n0 + j * 16 + lr;
            #pragma unroll
            for (int r = 0; r < 4; ++r)
                p.gh[(size_t)(m0 + wave * 16 + lq * 4 + r) * 768 + col] = acc[j][r];
        }
    }
}

// ============================ K4: combine -> u_bf (r7 body) =================
__global__ __launch_bounds__(256) void k_u2b(Params p) {
    const int row = blockIdx.x, t = threadIdx.x;
    const int b = row >> 3, i = row & 7;
    float acc = 0.f, rs = 0.f;
    #pragma unroll
    for (int c = 0; c < 16; ++c) {
        acc += p.upart[(((size_t)b * 16 + c) * 8 + i) * 256 + t];
        rs  += p.rspart[((size_t)b * 16 + c) * 8 + i];
    }
    p.u_bf[(size_t)row * 256 + t] = f2bf(acc / rs);
}

// ============================ K5: gi GEMM (4,12) ============================
__global__ __launch_bounds__(256) void k_gi(Params p) {
    __shared__ unsigned short As[64 * 32], Bs[64 * 32];
    const int m0 = blockIdx.x * 64, n0 = blockIdx.y * 64;
    const int t = threadIdx.x, wave = t >> 6, lane = t & 63;
    const int lr = lane & 15, lq = lane >> 4;
    f32x4 acc[4] = {};
    const int sr = t >> 2, sl = t & 3, gk = sl * 8;
    const int wsl = (sl ^ ((sr >> 1) & 3)) * 8;
    for (int k0 = 0; k0 < 256; k0 += 32) {
        __syncthreads();
        uint4 a0 = *(const uint4*)(p.u_bf   + (size_t)(m0 + sr) * 256 + k0 + gk);
        uint4 b0 = *(const uint4*)(p.wih_bf + (size_t)(n0 + sr) * 256 + k0 + gk);
        *(uint4*)(As + sr * 32 + wsl) = a0;
        *(uint4*)(Bs + sr * 32 + wsl) = b0;
        __syncthreads();
        const int ra = wave * 16 + lr;
        bf16x8 af = *(const bf16x8*)(As + ra * 32 + ((lq ^ ((ra >> 1) & 3)) * 8));
        #pragma unroll
        for (int j = 0; j < 4; ++j) {
            const int rb = j * 16 + lr;
            bf16x8 bv = *(const bf16x8*)(Bs + rb * 32 + ((lq ^ ((rb >> 1) & 3)) * 8));
            acc[j] = MFMA16(af, bv, acc[j]);
        }
    }
    #pragma unroll
    for (int j = 0; j < 4; ++j) {
        const int col = n0 + j * 16 + lr;
        #pragma unroll
        for (int r = 0; r < 4; ++r)
            p.gi[(size_t)(m0 + wave * 16 + lq * 4 + r) * 768 + col] = acc[j][r];
    }
}

// ============================ K6: GRU elementwise + LN_ff (r7 body) =========
__global__ __launch_bounds__(256) void k_gruln(Params p) {
    __shared__ float red[8];
    const int row = blockIdx.x, t = threadIdx.x;
    const float* gir = p.gi + (size_t)row * 768;
    const float* ghr = p.gh + (size_t)row * 768;
    const float ir  = gir[t]       + p.bih[t];
    const float iz  = gir[256 + t] + p.bih[256 + t];
    const float in_ = gir[512 + t] + p.bih[512 + t];
    const float hr  = ghr[t]       + p.bhh[t];
    const float hz  = ghr[256 + t] + p.bhh[256 + t];
    const float hn  = ghr[512 + t] + p.bhh[512 + t];
    const float r = 1.f / (1.f + __expf(-(ir + hr)));
    const float z = 1.f / (1.f + __expf(-(iz + hz)));
    const float n = tanhf(in_ + r * hn);
    const float h = p.slots[(size_t)row * 256 + t];
    const float s = (1.f - z) * n + z * h;
    p.slots[(size_t)row * 256 + t] = s;            // slots_mid (in place)
    float sm = s, ssq = s * s;
    #pragma unroll
    for (int o = 32; o > 0; o >>= 1) { sm += __shfl_down(sm, o); ssq += __shfl_down(ssq, o); }
    if ((t & 63) == 0) { red[t >> 6] = sm; red[4 + (t >> 6)] = ssq; }
    __syncthreads();
    const float S  = red[0] + red[1] + red[2] + red[3];
    const float SS = red[4] + red[5] + red[6] + red[7];
    const float mean = S * (1.f / 256.f);
    const float var  = SS * (1.f / 256.f) - mean * mean;
    const float rstd = rsqrtf(var + 1e-5f);
    p.ff_bf[(size_t)row * 256 + t] = f2bf((s - mean) * rstd * p.ln_ff_g[t] + p.ln_ff_b[t]);
}

// ============================ K7: MLP1 (relu -> bf16, r7 body) ==============
__global__ __launch_bounds__(256) void k_mlp1(Params p) {
    __shared__ unsigned short As[64 * 32], Bs[64 * 32];
    const int m0 = blockIdx.x * 64, n0 = blockIdx.y * 64;
    const int t = threadIdx.x, wave = t >> 6, lane = t & 63;
    const int lr = lane & 15, lq = lane >> 4;
    f32x4 acc[4] = {};
    const int sr = t >> 2, sl = t & 3, gk = sl * 8;
    const int wsl = (sl ^ ((sr >> 1) & 3)) * 8;
    for (int k0 = 0; k0 < 256; k0 += 32) {
        __syncthreads();
        uint4 a0 = *(const uint4*)(p.ff_bf + (size_t)(m0 + sr) * 256 + k0 + gk);
        uint4 b0 = *(const uint4*)(p.w1_bf + (size_t)(n0 + sr) * 256 + k0 + gk);
        *(uint4*)(As + sr * 32 + wsl) = a0;
        *(uint4*)(Bs + sr * 32 + wsl) = b0;
        __syncthreads();
        const int ra = wave * 16 + lr;
        bf16x8 af = *(const bf16x8*)(As + ra * 32 + ((lq ^ ((ra >> 1) & 3)) * 8));
        #pragma unroll
        for (int j = 0; j < 4; ++j) {
            const int rb = j * 16 + lr;
            bf16x8 bv = *(const bf16x8*)(Bs + rb * 32 + ((lq ^ ((rb >> 1) & 3)) * 8));
            acc[j] = MFMA16(af, bv, acc[j]);
        }
    }
    #pragma unroll
    for (int j = 0; j < 4; ++j) {
        const int col = n0 + j * 16 + lr;
        const float bb = p.b1[col];
        #pragma unroll
        for (int r = 0; r < 4; ++r) {
            const int row = m0 + wave * 16 + lq * 4 + r;
            p.h1_bf[(size_t)row * 1024 + col] = f2bf(fmaxf(acc[j][r] + bb, 0.f));
        }
    }
}

// ============================ K8: MLP2 partials (r7 body) ===================
__global__ __launch_bounds__(256) void k_out(Params p) {
    __shared__ unsigned short a_s[16][264];
    const int t = threadIdx.x;
    const int r0 = blockIdx.x * 16, kb = blockIdx.y * 256;
    const int row16 = t >> 4, sub = t & 15;
    {
        const unsigned short* src = p.h1_bf + (size_t)(r0 + row16) * 1024 + kb + sub * 16;
        *(uint4*)&a_s[row16][sub * 16]     = *(const uint4*)(src);
        *(uint4*)&a_s[row16][sub * 16 + 8] = *(const uint4*)(src + 8);
    }
    __syncthreads();
    const int w = t >> 6, lane = t & 63;
    const int lr = lane & 15, lq = lane >> 4;
    f32x4 acc[4] = {};
    for (int k0 = 0; k0 < 256; k0 += 32) {
        bf16x8 a = *(const bf16x8*)&a_s[lr][k0 + lq * 8];
        #pragma unroll
        for (int j = 0; j < 4; ++j) {
            bf16x8 bv = *(const bf16x8*)(p.w2_bf + (size_t)(w * 64 + j * 16 + lr) * 1024 + kb + k0 + lq * 8);
            acc[j] = MFMA16(a, bv, acc[j]);
        }
    }
    #pragma unroll
    for (int j = 0; j < 4; ++j)
        #pragma unroll
        for (int r = 0; r < 4; ++r)
            p.opart[((size_t)blockIdx.y * 256 + r0 + lq * 4 + r) * 256 + w * 64 + j * 16 + lr] = acc[j][r];
}

// ============================ K9: reduce + residual + LN + q (r7 body) ======
template<int LAST>
__global__ __launch_bounds__(256) void k_lnq(Params p) {
    __shared__ unsigned short u[16][264];
    const int t = threadIdx.x;
    const int r0 = blockIdx.x * 16;
    const int row16 = t >> 4, sub = t & 15;
    float vals[16]; float s_ = 0.f, ss = 0.f;
    #pragma unroll
    for (int k = 0; k < 16; ++k) {
        const int c = sub * 16 + k;
        const size_t ridx = (size_t)(r0 + row16) * 256 + c;
        float v = p.opart[(size_t)(r0 + row16) * 256 + c]
                + p.opart[((size_t)256 + r0 + row16) * 256 + c]
                + p.opart[((size_t)512 + r0 + row16) * 256 + c]
                + p.opart[((size_t)768 + r0 + row16) * 256 + c]
                + p.b2[c] + p.slots[ridx];
        if (LAST) { p.out[ridx] = v; }
        else {
            p.slots[ridx] = v;
            p.h_bf[ridx]  = f2bf(v);
        }
        vals[k] = v; s_ += v; ss += v * v;
    }
    if (LAST) return;
    #pragma unroll
    for (int m = 1; m < 16; m <<= 1) { s_ += __shfl_xor(s_, m); ss += __shfl_xor(ss, m); }
    const float mean = s_ * (1.f / 256.f);
    const float var  = ss * (1.f / 256.f) - mean * mean;
    const float rstd = rsqrtf(var + 1e-5f);
    #pragma unroll
    for (int k = 0; k < 16; ++k) {
        const int c = sub * 16 + k;
        u[row16][c] = f2bf((vals[k] - mean) * rstd * p.ln_s_g[c] + p.ln_s_b[c]);
    }
    __syncthreads();
    qgemm(p, u, r0);
}

// ---------------------------------------------------------------------------
extern "C" void kernel_launch(void* const* d_in, const int* in_sizes, int n_in,
                              void* d_out, int out_size, void* d_ws, size_t ws_size,
                              hipStream_t stream)
{
    (void)in_sizes; (void)n_in; (void)out_size; (void)ws_size;

    Params prm;
    prm.inputs  = (const float*)d_in[0];
    prm.noise   = (const float*)d_in[1];
    prm.mu      = (const float*)d_in[2];
    prm.ls      = (const float*)d_in[3];
    prm.Wq      = (const float*)d_in[4];
    prm.Wk      = (const float*)d_in[5];
    prm.Wv      = (const float*)d_in[6];
    prm.wih     = (const float*)d_in[7];
    prm.whh     = (const float*)d_in[8];
    prm.bih     = (const float*)d_in[9];
    prm.bhh     = (const float*)d_in[10];
    prm.w1      = (const float*)d_in[11];
    prm.b1      = (const float*)d_in[12];
    prm.w2      = (const float*)d_in[13];
    prm.b2      = (const float*)d_in[14];
    prm.ln_in_g = (const float*)d_in[15];
    prm.ln_in_b = (const float*)d_in[16];
    prm.ln_s_g  = (const float*)d_in[17];
    prm.ln_s_b  = (const float*)d_in[18];
    prm.ln_ff_g = (const float*)d_in[19];
    prm.ln_ff_b = (const float*)d_in[20];
    prm.out     = (float*)d_out;

    char* ptr = (char*)d_ws;
    auto alloc = [&](size_t bytes) -> char* {
        char* r = ptr; ptr += (bytes + 255) & ~(size_t)255; return r;
    };
    prm.x_bf   = (unsigned short*)alloc((size_t)32768 * 256 * 2);
    prm.kv_bf  = (unsigned short*)alloc((size_t)32768 * 512 * 2);
    prm.kvW_bf = (unsigned short*)alloc(512 * 256 * 2);
    prm.Wq_bf  = (unsigned short*)alloc(256 * 256 * 2);
    prm.wih_bf = (unsigned short*)alloc(768 * 256 * 2);
    prm.whh_bf = (unsigned short*)alloc(768 * 256 * 2);
    prm.w1_bf  = (unsigned short*)alloc(1024 * 256 * 2);
    prm.w2_bf  = (unsigned short*)alloc(256 * 1024 * 2);
    prm.slots  = (float*)         alloc(256 * 256 * 4);
    prm.q      = (float*)         alloc(256 * 256 * 4);
    prm.upart  = (float*)         alloc((size_t)32 * 16 * 8 * 256 * 4);
    prm.rspart = (float*)         alloc(32 * 16 * 8 * 4);
    prm.u_bf   = (unsigned short*)alloc(256 * 256 * 2);
    prm.h_bf   = (unsigned short*)alloc(256 * 256 * 2);
    prm.gi     = (float*)         alloc(256 * 768 * 4);
    prm.gh     = (float*)         alloc(256 * 768 * 4);
    prm.ff_bf  = (unsigned short*)alloc(256 * 256 * 2);
    prm.h1_bf  = (unsigned short*)alloc(256 * 1024 * 2);
    prm.opart  = (float*)         alloc((size_t)4 * 256 * 256 * 4);

    k_prep<<<4608, 256, 0, stream>>>(prm);
    k_kv  <<<1040, 256, 0, stream>>>(prm);
    for (int it = 0; it < 3; ++it) {
        k_attn_gh<<<560, 256, 0, stream>>>(prm);
        k_u2b    <<<256, 256, 0, stream>>>(prm);
        k_gi     <<<dim3(4, 12), 256, 0, stream>>>(prm);
        k_gruln  <<<256, 256, 0, stream>>>(prm);
        k_mlp1   <<<dim3(4, 16), 256, 0, stream>>>(prm);
        k_out    <<<dim3(16, 4), 256, 0, stream>>>(prm);
        if (it < 2) k_lnq<0><<<16, 256, 0, stream>>>(prm);
        else        k_lnq<1><<<16, 256, 0, stream>>>(prm);
    }
}